// Round 7
// baseline (146.029 us; speedup 1.0000x reference)
//
#include <hip/hip_runtime.h>
#include <hip/hip_bf16.h>
#include <math.h>

#define BB   64
#define TT   1000
#define DEC  1024
#define ENCD 512
#define ATT  128
#define FILT 32
#define KSZ  31
#define PADW 15
#define BT   128   // t-tile per block
#define KC   64    // K chunk (bf16)
#define XW   (BT + KSZ - 1)   // 158

typedef __attribute__((ext_vector_type(8))) short bf16x8;
typedef __attribute__((ext_vector_type(4))) float f32x4;

static __device__ __forceinline__ ushort f2bf(float f) {
    union { float f; unsigned u; } v; v.f = f;
    unsigned r = (v.u + 0x7FFFu + ((v.u >> 16) & 1u)) >> 16;   // RNE
    return (ushort)r;
}

// async global->LDS, 16B per lane; LDS dest = wave-uniform base + lane*16
static __device__ __forceinline__ void gl2lds16(const void* g, void* l) {
    __builtin_amdgcn_global_load_lds(
        (const __attribute__((address_space(1))) unsigned*)g,
        (__attribute__((address_space(3))) unsigned*)l, 16, 0, 0);
}

// ---------------- K0: pack B into fragment-major bf16 layout ------------------
// element index = (((c*2+ks)*8 + n)*64 + lane)*8 + j
//   a = n*16 + (lane&15),  k = c*64 + ks*32 + (lane>>4)*8 + j
//   k<512: key_w[a][k];  512<=k<544: loc_proj_w[a][k-512];  else 0
__global__ __launch_bounds__(256) void k_prep(const float* __restrict__ kw,
                                              const float* __restrict__ lpw,
                                              ushort* __restrict__ kwbF) {
    int idx = blockIdx.x * 256 + threadIdx.x;     // 0..9215
    int l  = idx & 63;
    int n  = (idx >> 6) & 7;
    int ks = (idx >> 9) & 1;
    int c  = idx >> 10;
    if (c >= 9) return;
    int a  = n * 16 + (l & 15);
    int k0 = c * 64 + ks * 32 + (l >> 4) * 8;
    ushort u[8];
    #pragma unroll
    for (int j = 0; j < 8; ++j) {
        int k = k0 + j;
        float v = 0.f;
        if (k < ENCD)             v = kw[a * ENCD + k];
        else if (k < ENCD + FILT) v = lpw[a * FILT + (k - ENCD)];
        u[j] = f2bf(v);
    }
    *(uint4*)&kwbF[(size_t)idx * 8] = *(const uint4*)u;
}

// ---------------- K1: query = decoder_hidden @ query_w^T  (64 x 128) ----------
__global__ __launch_bounds__(128) void k_query(const float* __restrict__ dh,
                                               const float* __restrict__ qw,
                                               float* __restrict__ q) {
    int b = blockIdx.x, a = threadIdx.x;
    const float* dhb = dh + b * DEC;
    const float* qwa = qw + a * DEC;
    float s = 0.f;
    #pragma unroll 4
    for (int k = 0; k < DEC; k += 4) {
        float4 x = *(const float4*)&dhb[k];
        float4 w = *(const float4*)&qwa[k];
        s += x.x * w.x + x.y * w.y + x.z * w.z + x.w * w.w;
    }
    q[b * ATT + a] = s;
}

// ---------------- K3: fused conv + double-buffered LDS MFMA GEMM --------------
__global__ __launch_bounds__(512, 2) void k_energies(
    const float* __restrict__ enc, const float* __restrict__ pw,
    const float* __restrict__ pwc, const float* __restrict__ cwg,
    const ushort* __restrict__ kwbF, const float* __restrict__ vw,
    const float* __restrict__ q, float* __restrict__ energ)
{
    __shared__ __align__(16) ushort Ab[2][BT * KC];        // 2 x 16 KB, swizzled
    __shared__ __align__(16) ushort Bb[2][2 * 8 * 64 * 8]; // 2 x 16 KB, frag-major linear
    __shared__ __align__(16) ushort featb[BT * FILT];      // 8 KB, compact swizzled
    // conv-phase overlays (dead once the main loop begins):
    float* cwl   = (float*)Ab[1];    // 1984 floats
    float* convx = (float*)Bb[1];    // 2 x 158 floats

    const int b   = blockIdx.x;
    const int t0  = blockIdx.y * BT;
    const int tid = threadIdx.x;
    const int w   = tid >> 6;
    const int l   = tid & 63;
    const int r   = l & 15;
    const int sl  = l >> 4;
    const int row = w * 16 + r;      // wave's t-row for MFMA reads

    const float* encb = enc + (size_t)b * TT * ENCD;

    // ---- B0 via async global->LDS (linear layout matches exactly) ----
    #pragma unroll
    for (int j = 0; j < 2; ++j)
        gl2lds16(kwbF + (size_t)(tid + j * 512) * 8,
                 &Bb[0][(size_t)(w * 64 + j * 512) * 8]);

    // ---- chunk-0 A staging loads (regs, coalesced) ----
    float4 areg[4];
    #pragma unroll
    for (int j = 0; j < 4; ++j) {
        int idx = tid + j * 512;
        int rw = idx >> 4, c4 = idx & 15;
        int tg = t0 + rw; if (tg >= TT) tg = TT - 1;
        areg[j] = *(const float4*)(encb + (size_t)tg * ENCD + c4 * 4);
    }

    // ---- conv staging (into overlays) ----
    if (tid < 496) {
        float4 v = *(const float4*)(cwg + tid * 4);
        *(float4*)&cwl[tid * 4] = v;
    }
    for (int i = tid; i < 2 * XW; i += 512) {
        int c  = i / XW;
        int tt = i - c * XW;
        int tg = t0 + tt - PADW;
        const float* src = c ? pwc : pw;
        convx[c * XW + tt] = (tg >= 0 && tg < TT) ? src[b * TT + tg] : 0.f;
    }
    __syncthreads();

    // ---- conv compute -> featb (compact [128][32], swizzled) ----
    #pragma unroll
    for (int i = 0; i < 8; ++i) {
        int idx = tid + i * 512;          // 0..4095
        int f = idx >> 7, tl = idx & 127;
        const float* c0 = cwl + (f * 2 + 0) * KSZ;
        const float* c1 = cwl + (f * 2 + 1) * KSZ;
        float s = 0.f;
        #pragma unroll
        for (int k = 0; k < KSZ; ++k)
            s += c0[k] * convx[tl + k] + c1[k] * convx[XW + tl + k];
        int byte = tl * 64 + ((((f >> 3) ^ (tl & 3)) << 4)) + (f & 7) * 2;
        *(ushort*)((char*)featb + byte) = f2bf(s);
    }

    // ---- write chunk-0 A into LDS buf 0 ----
    #pragma unroll
    for (int j = 0; j < 4; ++j) {
        int idx = tid + j * 512;
        int rw = idx >> 4, c4 = idx & 15;
        ushort u[4] = { f2bf(areg[j].x), f2bf(areg[j].y), f2bf(areg[j].z), f2bf(areg[j].w) };
        int byte = rw * 128 + ((((c4 >> 1) ^ (rw & 7)) << 4)) + (c4 & 1) * 8;
        *(uint2*)((char*)Ab[0] + byte) = *(const uint2*)u;
    }
    __syncthreads();   // drains vmcnt(0): B0 landed; featb + A0 ready; overlays dead

    // ---- MFMA K-loop: 8 enc chunks, double-buffered, fully unrolled ----
    f32x4 acc[8];
    #pragma unroll
    for (int n = 0; n < 8; ++n) acc[n] = (f32x4){0.f, 0.f, 0.f, 0.f};

    #pragma unroll
    for (int c = 0; c < 8; ++c) {
        const int buf = c & 1;
        // issue next-chunk staging (T14: issue early, write late)
        if (c < 7) {
            #pragma unroll
            for (int j = 0; j < 2; ++j)
                gl2lds16(kwbF + (size_t)(c + 1) * 8192 + (size_t)(tid + j * 512) * 8,
                         &Bb[buf ^ 1][(size_t)(w * 64 + j * 512) * 8]);
            #pragma unroll
            for (int j = 0; j < 4; ++j) {
                int idx = tid + j * 512;
                int rw = idx >> 4, c4 = idx & 15;
                int tg = t0 + rw; if (tg >= TT) tg = TT - 1;
                areg[j] = *(const float4*)(encb + (size_t)tg * ENCD + (c + 1) * KC + c4 * 4);
            }
        }

        // compute chunk c from LDS buf
        #pragma unroll
        for (int ks = 0; ks < 2; ++ks) {
            int s = ks * 4 + sl;
            bf16x8 af = *(const bf16x8*)((const char*)Ab[buf] + row * 128 + (((s ^ (row & 7)) << 4)));
            #pragma unroll
            for (int n = 0; n < 8; ++n) {
                bf16x8 bv = *(const bf16x8*)&Bb[buf][(size_t)((ks * 8 + n) * 64 + l) * 8];
                acc[n] = __builtin_amdgcn_mfma_f32_16x16x32_bf16(af, bv, acc[n], 0, 0, 0);
            }
        }

        // write staged A regs into the other buffer
        if (c < 7) {
            #pragma unroll
            for (int j = 0; j < 4; ++j) {
                int idx = tid + j * 512;
                int rw = idx >> 4, c4 = idx & 15;
                ushort u[4] = { f2bf(areg[j].x), f2bf(areg[j].y), f2bf(areg[j].z), f2bf(areg[j].w) };
                int byte = rw * 128 + ((((c4 >> 1) ^ (rw & 7)) << 4)) + (c4 & 1) * 8;
                *(uint2*)((char*)Ab[buf ^ 1] + byte) = *(const uint2*)u;
            }
        }
        __syncthreads();   // also drains vmcnt(0) -> next B buffer landed
    }

    // ---- feat chunk (K=32): A from featb, B direct from L2 (8 KB, read once) ----
    {
        bf16x8 af = *(const bf16x8*)((const char*)featb + row * 64 + (((sl ^ (row & 3)) << 4)));
        #pragma unroll
        for (int n = 0; n < 8; ++n) {
            bf16x8 bv = *(const bf16x8*)(kwbF + (size_t)(128 + n) * 512 + l * 8);
            acc[n] = __builtin_amdgcn_mfma_f32_16x16x32_bf16(af, bv, acc[n], 0, 0, 0);
        }
    }

    // ---- epilogue: + query, tanh, v-dot, reduce over a ----
    const float* qb = q + b * ATT;
    float pe[4];
    #pragma unroll
    for (int rr = 0; rr < 4; ++rr) pe[rr] = 0.f;
    #pragma unroll
    for (int n = 0; n < 8; ++n) {
        int a = n * 16 + r;
        float vvn = vw[a];
        float qvn = qb[a];
        #pragma unroll
        for (int rr = 0; rr < 4; ++rr)
            pe[rr] += vvn * tanhf(acc[n][rr] + qvn);
    }
    #pragma unroll
    for (int m = 1; m < 16; m <<= 1) {
        #pragma unroll
        for (int rr = 0; rr < 4; ++rr)
            pe[rr] += __shfl_xor(pe[rr], m, 64);
    }
    if (r == 0) {
        #pragma unroll
        for (int rr = 0; rr < 4; ++rr) {
            int t = t0 + w * 16 + sl * 4 + rr;
            if (t < TT) energ[b * TT + t] = pe[rr];
        }
    }
}

// ---------------- K4: softmax over T per batch row ----------------------------
__global__ __launch_bounds__(256) void k_softmax(const float* __restrict__ energ,
                                                 const unsigned char* __restrict__ mask,
                                                 float* __restrict__ wout) {
    int b = blockIdx.x, tid = threadIdx.x;
    __shared__ float sred[8];
    const float* eb = energ + b * TT;
    const unsigned char* mb = mask + b * TT;
    float m = -INFINITY;
    for (int t = tid; t < TT; t += 256) {
        float e = mb[t] ? -INFINITY : eb[t];
        m = fmaxf(m, e);
    }
    #pragma unroll
    for (int off = 32; off; off >>= 1) m = fmaxf(m, __shfl_xor(m, off, 64));
    if ((tid & 63) == 0) sred[tid >> 6] = m;
    __syncthreads();
    m = fmaxf(fmaxf(sred[0], sred[1]), fmaxf(sred[2], sred[3]));
    float s = 0.f;
    for (int t = tid; t < TT; t += 256) {
        float e = mb[t] ? -INFINITY : eb[t];
        s += expf(e - m);
    }
    #pragma unroll
    for (int off = 32; off; off >>= 1) s += __shfl_xor(s, off, 64);
    if ((tid & 63) == 0) sred[4 + (tid >> 6)] = s;
    __syncthreads();
    s = sred[4] + sred[5] + sred[6] + sred[7];
    float inv = 1.f / s;
    float* wb = wout + b * TT;
    for (int t = tid; t < TT; t += 256) {
        float e = mb[t] ? -INFINITY : eb[t];
        wb[t] = expf(e - m) * inv;
    }
}

// ---------------- K5: partial context (8 t-chunks of 125) ---------------------
#define TCH 125
__global__ __launch_bounds__(512) void k_ctx_partial(const float* __restrict__ enc,
                                                     const float* __restrict__ w,
                                                     float* __restrict__ partial) {
    int b = blockIdx.x, c = blockIdx.y;
    int e = threadIdx.x;
    __shared__ float sw[TCH];
    int tstart = c * TCH;
    if (threadIdx.x < TCH) sw[threadIdx.x] = w[b * TT + tstart + threadIdx.x];
    __syncthreads();
    const float* p = enc + ((size_t)b * TT + tstart) * ENCD + e;
    float acc = 0.f;
    #pragma unroll 5
    for (int t = 0; t < TCH; ++t)
        acc += sw[t] * p[(size_t)t * ENCD];
    partial[((b << 3) + c) * ENCD + e] = acc;
}

// ---------------- K6: reduce partials -> context ------------------------------
__global__ __launch_bounds__(512) void k_ctx_reduce(const float* __restrict__ partial,
                                                    float* __restrict__ ctx) {
    int b = blockIdx.x, e = threadIdx.x;
    float s = 0.f;
    #pragma unroll
    for (int c = 0; c < 8; ++c) s += partial[((b << 3) + c) * ENCD + e];
    ctx[b * ENCD + e] = s;
}

// ---------------- launcher ----------------------------------------------------
extern "C" void kernel_launch(void* const* d_in, const int* in_sizes, int n_in,
                              void* d_out, int out_size, void* d_ws, size_t ws_size,
                              hipStream_t stream) {
    const float* dh   = (const float*)d_in[0];
    const float* enc  = (const float*)d_in[1];
    const float* pw   = (const float*)d_in[2];
    const float* pwc  = (const float*)d_in[3];
    const unsigned char* mask = (const unsigned char*)d_in[4];
    const float* cw   = (const float*)d_in[5];
    const float* lpw  = (const float*)d_in[6];
    const float* qw   = (const float*)d_in[7];
    const float* kw   = (const float*)d_in[8];
    const float* vw   = (const float*)d_in[9];

    float* out_ctx = (float*)d_out;                 // (64, 512)
    float* out_w   = out_ctx + BB * ENCD;           // (64, 1000)

    float* wsf   = (float*)d_ws;
    float*  q     = wsf;                             // 8192 f
    float*  energ = wsf + 8192;                      // 64000 f
    float*  part  = wsf + 8192 + 64000;              // 32768 f
    ushort* kwbF  = (ushort*)(wsf + 8192 + 64000 + 32768);  // 73728 bf16

    k_prep    <<<dim3(36),    dim3(256), 0, stream>>>(kw, lpw, kwbF);
    k_query   <<<dim3(BB),    dim3(128), 0, stream>>>(dh, qw, q);
    k_energies<<<dim3(BB, 8), dim3(512), 0, stream>>>(enc, pw, pwc, cw, kwbF, vw, q, energ);
    k_softmax <<<dim3(BB),    dim3(256), 0, stream>>>(energ, mask, out_w);
    k_ctx_partial<<<dim3(BB, 8), dim3(512), 0, stream>>>(enc, out_w, part);
    k_ctx_reduce <<<dim3(BB),    dim3(512), 0, stream>>>(part, out_ctx);
}

// Round 8
// 117.218 us; speedup vs baseline: 1.2458x; 1.2458x over previous
//
#include <hip/hip_runtime.h>
#include <hip/hip_bf16.h>
#include <math.h>

#define BB   64
#define TT   1000
#define DEC  1024
#define ENCD 512
#define ATT  128
#define FILT 32
#define KSZ  31
#define PADW 15
#define BT   128   // t-tile per block
#define KC   64    // K chunk
#define XW   (BT + KSZ - 1)   // 158

typedef __attribute__((ext_vector_type(8))) short bf16x8;
typedef __attribute__((ext_vector_type(4))) float f32x4;

static __device__ __forceinline__ ushort f2bf(float f) {
    union { float f; unsigned u; } v; v.f = f;
    unsigned r = (v.u + 0x7FFFu + ((v.u >> 16) & 1u)) >> 16;   // RNE
    return (ushort)r;
}

// async global->LDS, 16B per lane; LDS dest = wave-uniform base + lane*16
static __device__ __forceinline__ void gl2lds16(const void* g, void* l) {
    __builtin_amdgcn_global_load_lds(
        (const __attribute__((address_space(1))) unsigned*)g,
        (__attribute__((address_space(3))) unsigned*)l, 16, 0, 0);
}

// ---------------- K0: pack B into fragment-major bf16 layout ------------------
// element index = (((c*2+ks)*8 + n)*64 + lane)*8 + j
//   a = n*16 + (lane&15),  k = c*64 + ks*32 + (lane>>4)*8 + j
__global__ __launch_bounds__(256) void k_prep(const float* __restrict__ kw,
                                              const float* __restrict__ lpw,
                                              ushort* __restrict__ kwbF) {
    int idx = blockIdx.x * 256 + threadIdx.x;     // 0..9215
    int l  = idx & 63;
    int n  = (idx >> 6) & 7;
    int ks = (idx >> 9) & 1;
    int c  = idx >> 10;
    if (c >= 9) return;
    int a  = n * 16 + (l & 15);
    int k0 = c * 64 + ks * 32 + (l >> 4) * 8;
    ushort u[8];
    #pragma unroll
    for (int j = 0; j < 8; ++j) {
        int k = k0 + j;
        float v = 0.f;
        if (k < ENCD)             v = kw[a * ENCD + k];
        else if (k < ENCD + FILT) v = lpw[a * FILT + (k - ENCD)];
        u[j] = f2bf(v);
    }
    *(uint4*)&kwbF[(size_t)idx * 8] = *(const uint4*)u;
}

// ---------------- K1: query = decoder_hidden @ query_w^T  (64 x 128) ----------
__global__ __launch_bounds__(128) void k_query(const float* __restrict__ dh,
                                               const float* __restrict__ qw,
                                               float* __restrict__ q) {
    int b = blockIdx.x, a = threadIdx.x;
    const float* dhb = dh + b * DEC;
    const float* qwa = qw + a * DEC;
    float s = 0.f;
    #pragma unroll 4
    for (int k = 0; k < DEC; k += 4) {
        float4 x = *(const float4*)&dhb[k];
        float4 w = *(const float4*)&qwa[k];
        s += x.x * w.x + x.y * w.y + x.z * w.z + x.w * w.w;
    }
    q[b * ATT + a] = s;
}

// ---------------- K3: fused conv + dbuf LDS MFMA GEMM (A staged f32) ----------
// A tile: f32 [128 rows][16 x 16B-units], unit position swizzled c4' = c4 ^ ((row&7)<<1)
// staged by global_load_lds with pre-swizzled per-lane SOURCE (linear LDS dest).
__global__ __launch_bounds__(512) void k_energies(
    const float* __restrict__ enc, const float* __restrict__ pw,
    const float* __restrict__ pwc, const float* __restrict__ cwg,
    const ushort* __restrict__ kwbF, const float* __restrict__ vw,
    const float* __restrict__ q, float* __restrict__ energ)
{
    __shared__ __align__(16) float  Ab[2][BT * 64];        // 2 x 32 KB, f32 swizzled
    __shared__ __align__(16) ushort Bb[2][2 * 8 * 64 * 8]; // 2 x 16 KB, frag-major linear
    __shared__ __align__(16) ushort featb[BT * FILT];      // 8 KB, compact swizzled
    // conv-phase overlays (dead once the main loop begins):
    float* cwl   = (float*)Ab[1];    // 1984 floats
    float* convx = (float*)Bb[1];    // 2 x 158 floats

    const int b   = blockIdx.x;
    const int t0  = blockIdx.y * BT;
    const int tid = threadIdx.x;
    const int w   = tid >> 6;
    const int l   = tid & 63;
    const int r   = l & 15;
    const int sl  = l >> 4;
    const int row = w * 16 + r;      // wave's t-row for MFMA reads

    const float* encb = enc + (size_t)b * TT * ENCD;

    // per-lane pre-swizzled A source pointers (issue j covers rows (j*8+w)*4 .. +3)
    const float* aSrc[4];
    #pragma unroll
    for (int j = 0; j < 4; ++j) {
        int rw  = (j * 8 + w) * 4 + (l >> 4);          // row this lane feeds
        int c4  = (l & 15) ^ ((rw & 7) << 1);          // inverse-swizzled source unit
        int tg  = t0 + rw; if (tg >= TT) tg = TT - 1;
        aSrc[j] = encb + (size_t)tg * ENCD + c4 * 4;
    }

    // ---- issue chunk-0 staging: B0 and A0 via async global->LDS ----
    #pragma unroll
    for (int j = 0; j < 2; ++j)
        gl2lds16(kwbF + (size_t)(tid + j * 512) * 8,
                 &Bb[0][(size_t)(w * 64 + j * 512) * 8]);
    #pragma unroll
    for (int j = 0; j < 4; ++j)
        gl2lds16(aSrc[j], (char*)Ab[0] + (j * 8 + w) * 1024);

    // ---- conv staging (into overlays) ----
    if (tid < 496) {
        float4 v = *(const float4*)(cwg + tid * 4);
        *(float4*)&cwl[tid * 4] = v;
    }
    for (int i = tid; i < 2 * XW; i += 512) {
        int c  = i / XW;
        int tt = i - c * XW;
        int tg = t0 + tt - PADW;
        const float* src = c ? pwc : pw;
        convx[c * XW + tt] = (tg >= 0 && tg < TT) ? src[b * TT + tg] : 0.f;
    }
    __syncthreads();   // overlays staged; chunk-0 gl2lds drained

    // ---- conv compute -> featb (compact [128][32] bf16, swizzled) ----
    #pragma unroll
    for (int i = 0; i < 8; ++i) {
        int idx = tid + i * 512;          // 0..4095
        int f = idx >> 7, tl = idx & 127;
        const float* c0 = cwl + (f * 2 + 0) * KSZ;
        const float* c1 = cwl + (f * 2 + 1) * KSZ;
        float s = 0.f;
        #pragma unroll
        for (int k = 0; k < KSZ; ++k)
            s += c0[k] * convx[tl + k] + c1[k] * convx[XW + tl + k];
        int byte = tl * 64 + ((((f >> 3) ^ (tl & 3)) << 4)) + (f & 7) * 2;
        *(ushort*)((char*)featb + byte) = f2bf(s);
    }
    __syncthreads();   // conv reads of overlays done; featb ready

    // ---- MFMA K-loop: 8 enc chunks, double-buffered ----
    f32x4 acc[8];
    #pragma unroll
    for (int n = 0; n < 8; ++n) acc[n] = (f32x4){0.f, 0.f, 0.f, 0.f};

    #pragma unroll
    for (int c = 0; c < 8; ++c) {
        const int buf = c & 1;
        // prefetch chunk c+1 into the other buffers (overlays dead after barrier above)
        if (c < 7) {
            #pragma unroll
            for (int j = 0; j < 4; ++j)
                gl2lds16(aSrc[j] + (c + 1) * KC, (char*)Ab[buf ^ 1] + (j * 8 + w) * 1024);
            #pragma unroll
            for (int j = 0; j < 2; ++j)
                gl2lds16(kwbF + (size_t)(c + 1) * 8192 + (size_t)(tid + j * 512) * 8,
                         &Bb[buf ^ 1][(size_t)(w * 64 + j * 512) * 8]);
        }

        // compute chunk c: A fragments read f32-swizzled, convert, MFMA
        #pragma unroll
        for (int ks = 0; ks < 2; ++ks) {
            int s   = ks * 4 + sl;
            int c4p = (2 * s) ^ ((row & 7) << 1);
            const char* ap = (const char*)Ab[buf] + row * 256 + c4p * 16;
            float4 alo = *(const float4*)ap;
            float4 ahi = *(const float4*)(ap + 16);
            ushort u[8] = { f2bf(alo.x), f2bf(alo.y), f2bf(alo.z), f2bf(alo.w),
                            f2bf(ahi.x), f2bf(ahi.y), f2bf(ahi.z), f2bf(ahi.w) };
            bf16x8 af = *(const bf16x8*)u;
            #pragma unroll
            for (int n = 0; n < 8; ++n) {
                bf16x8 bv = *(const bf16x8*)&Bb[buf][(size_t)((ks * 8 + n) * 64 + l) * 8];
                acc[n] = __builtin_amdgcn_mfma_f32_16x16x32_bf16(af, bv, acc[n], 0, 0, 0);
            }
        }
        __syncthreads();   // drains vmcnt(0) -> next buffers landed
    }

    // ---- feat chunk (K=32): A from featb, B direct from L2 (8 KB, read once) ----
    {
        bf16x8 af = *(const bf16x8*)((const char*)featb + row * 64 + (((sl ^ (row & 3)) << 4)));
        #pragma unroll
        for (int n = 0; n < 8; ++n) {
            bf16x8 bv = *(const bf16x8*)(kwbF + (size_t)(128 + n) * 512 + l * 8);
            acc[n] = __builtin_amdgcn_mfma_f32_16x16x32_bf16(af, bv, acc[n], 0, 0, 0);
        }
    }

    // ---- epilogue: + query, tanh, v-dot, reduce over a ----
    const float* qb = q + b * ATT;
    float pe[4];
    #pragma unroll
    for (int rr = 0; rr < 4; ++rr) pe[rr] = 0.f;
    #pragma unroll
    for (int n = 0; n < 8; ++n) {
        int a = n * 16 + r;
        float vvn = vw[a];
        float qvn = qb[a];
        #pragma unroll
        for (int rr = 0; rr < 4; ++rr)
            pe[rr] += vvn * tanhf(acc[n][rr] + qvn);
    }
    #pragma unroll
    for (int m = 1; m < 16; m <<= 1) {
        #pragma unroll
        for (int rr = 0; rr < 4; ++rr)
            pe[rr] += __shfl_xor(pe[rr], m, 64);
    }
    if (r == 0) {
        #pragma unroll
        for (int rr = 0; rr < 4; ++rr) {
            int t = t0 + w * 16 + sl * 4 + rr;
            if (t < TT) energ[b * TT + t] = pe[rr];
        }
    }
}

// ---------------- K4: softmax over T per batch row ----------------------------
__global__ __launch_bounds__(256) void k_softmax(const float* __restrict__ energ,
                                                 const unsigned char* __restrict__ mask,
                                                 float* __restrict__ wout) {
    int b = blockIdx.x, tid = threadIdx.x;
    __shared__ float sred[8];
    const float* eb = energ + b * TT;
    const unsigned char* mb = mask + b * TT;
    float m = -INFINITY;
    for (int t = tid; t < TT; t += 256) {
        float e = mb[t] ? -INFINITY : eb[t];
        m = fmaxf(m, e);
    }
    #pragma unroll
    for (int off = 32; off; off >>= 1) m = fmaxf(m, __shfl_xor(m, off, 64));
    if ((tid & 63) == 0) sred[tid >> 6] = m;
    __syncthreads();
    m = fmaxf(fmaxf(sred[0], sred[1]), fmaxf(sred[2], sred[3]));
    float s = 0.f;
    for (int t = tid; t < TT; t += 256) {
        float e = mb[t] ? -INFINITY : eb[t];
        s += expf(e - m);
    }
    #pragma unroll
    for (int off = 32; off; off >>= 1) s += __shfl_xor(s, off, 64);
    if ((tid & 63) == 0) sred[4 + (tid >> 6)] = s;
    __syncthreads();
    s = sred[4] + sred[5] + sred[6] + sred[7];
    float inv = 1.f / s;
    float* wb = wout + b * TT;
    for (int t = tid; t < TT; t += 256) {
        float e = mb[t] ? -INFINITY : eb[t];
        wb[t] = expf(e - m) * inv;
    }
}

// ---------------- K5: partial context (8 t-chunks of 125) ---------------------
#define TCH 125
__global__ __launch_bounds__(512) void k_ctx_partial(const float* __restrict__ enc,
                                                     const float* __restrict__ w,
                                                     float* __restrict__ partial) {
    int b = blockIdx.x, c = blockIdx.y;
    int e = threadIdx.x;
    __shared__ float sw[TCH];
    int tstart = c * TCH;
    if (threadIdx.x < TCH) sw[threadIdx.x] = w[b * TT + tstart + threadIdx.x];
    __syncthreads();
    const float* p = enc + ((size_t)b * TT + tstart) * ENCD + e;
    float acc = 0.f;
    #pragma unroll 5
    for (int t = 0; t < TCH; ++t)
        acc += sw[t] * p[(size_t)t * ENCD];
    partial[((b << 3) + c) * ENCD + e] = acc;
}

// ---------------- K6: reduce partials -> context ------------------------------
__global__ __launch_bounds__(512) void k_ctx_reduce(const float* __restrict__ partial,
                                                    float* __restrict__ ctx) {
    int b = blockIdx.x, e = threadIdx.x;
    float s = 0.f;
    #pragma unroll
    for (int c = 0; c < 8; ++c) s += partial[((b << 3) + c) * ENCD + e];
    ctx[b * ENCD + e] = s;
}

// ---------------- launcher ----------------------------------------------------
extern "C" void kernel_launch(void* const* d_in, const int* in_sizes, int n_in,
                              void* d_out, int out_size, void* d_ws, size_t ws_size,
                              hipStream_t stream) {
    const float* dh   = (const float*)d_in[0];
    const float* enc  = (const float*)d_in[1];
    const float* pw   = (const float*)d_in[2];
    const float* pwc  = (const float*)d_in[3];
    const unsigned char* mask = (const unsigned char*)d_in[4];
    const float* cw   = (const float*)d_in[5];
    const float* lpw  = (const float*)d_in[6];
    const float* qw   = (const float*)d_in[7];
    const float* kw   = (const float*)d_in[8];
    const float* vw   = (const float*)d_in[9];

    float* out_ctx = (float*)d_out;                 // (64, 512)
    float* out_w   = out_ctx + BB * ENCD;           // (64, 1000)

    float* wsf   = (float*)d_ws;
    float*  q     = wsf;                             // 8192 f
    float*  energ = wsf + 8192;                      // 64000 f
    float*  part  = wsf + 8192 + 64000;              // 32768 f
    ushort* kwbF  = (ushort*)(wsf + 8192 + 64000 + 32768);  // 73728 bf16

    k_prep    <<<dim3(36),    dim3(256), 0, stream>>>(kw, lpw, kwbF);
    k_query   <<<dim3(BB),    dim3(128), 0, stream>>>(dh, qw, q);
    k_energies<<<dim3(BB, 8), dim3(512), 0, stream>>>(enc, pw, pwc, cw, kwbF, vw, q, energ);
    k_softmax <<<dim3(BB),    dim3(256), 0, stream>>>(energ, mask, out_w);
    k_ctx_partial<<<dim3(BB, 8), dim3(512), 0, stream>>>(enc, out_w, part);
    k_ctx_reduce <<<dim3(BB),    dim3(512), 0, stream>>>(part, out_ctx);
}

// Round 9
// 96.237 us; speedup vs baseline: 1.5174x; 1.2180x over previous
//
#include <hip/hip_runtime.h>
#include <hip/hip_bf16.h>
#include <math.h>

#define BB   64
#define TT   1000
#define DEC  1024
#define ENCD 512
#define ATT  128
#define FILT 32
#define KSZ  31
#define PADW 15
#define BT   128   // t-tile per block
#define KC   64    // K chunk
#define XWN  160   // x-window alloc (158 used)

typedef __attribute__((ext_vector_type(8))) short bf16x8;
typedef __attribute__((ext_vector_type(4))) float f32x4;

static __device__ __forceinline__ ushort f2bf(float f) {
    union { float f; unsigned u; } v; v.f = f;
    unsigned r = (v.u + 0x7FFFu + ((v.u >> 16) & 1u)) >> 16;   // RNE
    return (ushort)r;
}

static __device__ __forceinline__ float fast_tanh(float x) {
    // tanh(x) = 1 - 2/(e^{2x}+1); exact limits at +-inf (exp->inf/0)
    float e = __expf(2.f * x);
    return 1.f - 2.f * __builtin_amdgcn_rcpf(e + 1.f);
}

// async global->LDS, 16B per lane; LDS dest = wave-uniform base + lane*16
static __device__ __forceinline__ void gl2lds16(const void* g, void* l) {
    __builtin_amdgcn_global_load_lds(
        (const __attribute__((address_space(1))) unsigned*)g,
        (__attribute__((address_space(3))) unsigned*)l, 16, 0, 0);
}

// ---------------- K0a: pack key_w into fragment-major bf16 (chunks 0..7) ------
// element index = (((c*2+ks)*8 + n)*64 + lane)*8 + j
//   a = n*16 + (lane&15),  k = c*64 + ks*32 + (lane>>4)*8 + j   (k < 512)
__global__ __launch_bounds__(256) void k_prep(const float* __restrict__ kw,
                                              ushort* __restrict__ kwbF) {
    int idx = blockIdx.x * 256 + threadIdx.x;     // 0..8191
    int l  = idx & 63;
    int n  = (idx >> 6) & 7;
    int ks = (idx >> 9) & 1;
    int c  = idx >> 10;
    int a  = n * 16 + (l & 15);
    int k0 = c * 64 + ks * 32 + (l >> 4) * 8;
    ushort u[8];
    #pragma unroll
    for (int j = 0; j < 8; ++j) u[j] = f2bf(kw[a * ENCD + k0 + j]);
    *(uint4*)&kwbF[(size_t)idx * 8] = *(const uint4*)u;
}

// ---------------- K0b: W2 = conv_w (x) loc_proj -> chunk 8, fragment-major ----
// W2[c][k][a] = sum_f conv_w[f][c][k] * loc_proj_w[a][f];  k==31 row = 0
__global__ __launch_bounds__(256) void k_prepW2(const float* __restrict__ cw,
                                                const float* __restrict__ lpw,
                                                ushort* __restrict__ kwbF) {
    int idx = blockIdx.x * 256 + threadIdx.x;     // 0..1023
    int l  = idx & 63;
    int n  = (idx >> 6) & 7;
    int ks = (idx >> 9) & 1;                      // = conv input channel c
    int a  = n * 16 + (l & 15);
    int s  = l >> 4;
    ushort u[8];
    #pragma unroll
    for (int j = 0; j < 8; ++j) {
        int k = s * 8 + j;
        float v = 0.f;
        if (k < KSZ) {
            #pragma unroll
            for (int f = 0; f < FILT; ++f)
                v += cw[(f * 2 + ks) * KSZ + k] * lpw[a * FILT + f];
        }
        u[j] = f2bf(v);
    }
    *(uint4*)&kwbF[(size_t)(((16 + ks) * 8 + n) * 64 + l) * 8] = *(const uint4*)u;
}

// ---------------- K1: query = decoder_hidden @ query_w^T  (64 x 128) ----------
__global__ __launch_bounds__(128) void k_query(const float* __restrict__ dh,
                                               const float* __restrict__ qw,
                                               float* __restrict__ q) {
    int b = blockIdx.x, a = threadIdx.x;
    const float* dhb = dh + b * DEC;
    const float* qwa = qw + a * DEC;
    float s = 0.f;
    #pragma unroll 4
    for (int k = 0; k < DEC; k += 4) {
        float4 x = *(const float4*)&dhb[k];
        float4 w = *(const float4*)&qwa[k];
        s += x.x * w.x + x.y * w.y + x.z * w.z + x.w * w.w;
    }
    q[b * ATT + a] = s;
}

// ---------------- K3: MFMA GEMM over K=576 (8 enc chunks + 1 im2col chunk) ----
// A tile: f32 [128 rows][16 x 16B-units], unit pos swizzled c4' = c4 ^ ((row&7)<<1),
// staged via global_load_lds with pre-swizzled per-lane SOURCE (linear LDS dest).
__global__ __launch_bounds__(512) void k_energies(
    const float* __restrict__ enc, const float* __restrict__ pw,
    const float* __restrict__ pwc, const ushort* __restrict__ kwbF,
    const float* __restrict__ vw, const float* __restrict__ q,
    float* __restrict__ energ)
{
    __shared__ __align__(16) float  Ab[BT * 64];        // 32 KB f32 swizzled
    __shared__ __align__(16) ushort Bb[2 * 8 * 64 * 8]; // 16 KB frag-major linear
    __shared__ __align__(16) float  xw[2][XWN];         // 1.3 KB im2col window

    const int b   = blockIdx.x;
    const int t0  = blockIdx.y * BT;
    const int tid = threadIdx.x;
    const int w   = tid >> 6;
    const int l   = tid & 63;
    const int r   = l & 15;
    const int sl  = l >> 4;
    const int row = w * 16 + r;      // wave's t-row for MFMA reads

    const float* encb = enc + (size_t)b * TT * ENCD;

    // per-lane pre-swizzled A source pointers (issue j covers rows (j*8+w)*4 .. +3)
    const float* aSrc[4];
    #pragma unroll
    for (int j = 0; j < 4; ++j) {
        int rw  = (j * 8 + w) * 4 + (l >> 4);          // row this lane feeds
        int c4  = (l & 15) ^ ((rw & 7) << 1);          // inverse-swizzled source unit
        int tg  = t0 + rw; if (tg >= TT) tg = TT - 1;
        aSrc[j] = encb + (size_t)tg * ENCD + c4 * 4;
    }

    // ---- stage x-window (zero-padded; finite everywhere) ----
    for (int i = tid; i < 2 * XWN; i += 512) {
        int c  = i / XWN;
        int ii = i - c * XWN;
        int tg = t0 + ii - PADW;
        const float* src = c ? pwc : pw;
        xw[c][ii] = (ii < BT + KSZ - 1 && tg >= 0 && tg < TT) ? src[b * TT + tg] : 0.f;
    }

    f32x4 acc[8];
    #pragma unroll
    for (int n = 0; n < 8; ++n) acc[n] = (f32x4){0.f, 0.f, 0.f, 0.f};

    for (int c = 0; c < 9; ++c) {
        if (c) __syncthreads();              // WAR: previous compute done with buffers
        // stage B chunk c (linear frag-major)
        #pragma unroll
        for (int j = 0; j < 2; ++j)
            gl2lds16(kwbF + (size_t)c * 8192 + (size_t)(tid + j * 512) * 8,
                     &Bb[(size_t)(w * 64 + j * 512) * 8]);
        // stage A chunk c (enc chunks only)
        if (c < 8) {
            #pragma unroll
            for (int j = 0; j < 4; ++j)
                gl2lds16(aSrc[j] + c * KC, (char*)Ab + (j * 8 + w) * 1024);
        }
        __syncthreads();                     // drains vmcnt(0): buffers ready

        #pragma unroll
        for (int ks = 0; ks < 2; ++ks) {
            bf16x8 af;
            if (c < 8) {
                int s   = ks * 4 + sl;
                int c4p = (2 * s) ^ ((row & 7) << 1);
                const char* ap = (const char*)Ab + row * 256 + c4p * 16;
                float4 alo = *(const float4*)ap;
                float4 ahi = *(const float4*)(ap + 16);
                ushort u[8] = { f2bf(alo.x), f2bf(alo.y), f2bf(alo.z), f2bf(alo.w),
                                f2bf(ahi.x), f2bf(ahi.y), f2bf(ahi.z), f2bf(ahi.w) };
                af = *(const bf16x8*)u;
            } else {
                // im2col fragment: A[t][ks*32 + sl*8 + j] = xw[ks][t + sl*8 + j]
                const float* xp = &xw[ks][row + sl * 8];
                ushort u[8] = { f2bf(xp[0]), f2bf(xp[1]), f2bf(xp[2]), f2bf(xp[3]),
                                f2bf(xp[4]), f2bf(xp[5]), f2bf(xp[6]), f2bf(xp[7]) };
                af = *(const bf16x8*)u;
            }
            #pragma unroll
            for (int n = 0; n < 8; ++n) {
                bf16x8 bv = *(const bf16x8*)&Bb[(size_t)((ks * 8 + n) * 64 + l) * 8];
                acc[n] = __builtin_amdgcn_mfma_f32_16x16x32_bf16(af, bv, acc[n], 0, 0, 0);
            }
        }
    }

    // ---- epilogue: + query, tanh, v-dot, reduce over a (16 lanes) ----
    const float* qb = q + b * ATT;
    float pe[4];
    #pragma unroll
    for (int rr = 0; rr < 4; ++rr) pe[rr] = 0.f;
    #pragma unroll
    for (int n = 0; n < 8; ++n) {
        int a = n * 16 + r;
        float vvn = vw[a];
        float qvn = qb[a];
        #pragma unroll
        for (int rr = 0; rr < 4; ++rr)
            pe[rr] += vvn * fast_tanh(acc[n][rr] + qvn);
    }
    #pragma unroll
    for (int m = 1; m < 16; m <<= 1) {
        #pragma unroll
        for (int rr = 0; rr < 4; ++rr)
            pe[rr] += __shfl_xor(pe[rr], m, 64);
    }
    if (r == 0) {
        #pragma unroll
        for (int rr = 0; rr < 4; ++rr) {
            int t = t0 + w * 16 + sl * 4 + rr;
            if (t < TT) energ[b * TT + t] = pe[rr];
        }
    }
}

// ---------------- K4: softmax over T per batch row ----------------------------
__global__ __launch_bounds__(256) void k_softmax(const float* __restrict__ energ,
                                                 const unsigned char* __restrict__ mask,
                                                 float* __restrict__ wout) {
    int b = blockIdx.x, tid = threadIdx.x;
    __shared__ float sred[8];
    const float* eb = energ + b * TT;
    const unsigned char* mb = mask + b * TT;
    float m = -INFINITY;
    for (int t = tid; t < TT; t += 256) {
        float e = mb[t] ? -INFINITY : eb[t];
        m = fmaxf(m, e);
    }
    #pragma unroll
    for (int off = 32; off; off >>= 1) m = fmaxf(m, __shfl_xor(m, off, 64));
    if ((tid & 63) == 0) sred[tid >> 6] = m;
    __syncthreads();
    m = fmaxf(fmaxf(sred[0], sred[1]), fmaxf(sred[2], sred[3]));
    float s = 0.f;
    for (int t = tid; t < TT; t += 256) {
        float e = mb[t] ? -INFINITY : eb[t];
        s += expf(e - m);
    }
    #pragma unroll
    for (int off = 32; off; off >>= 1) s += __shfl_xor(s, off, 64);
    if ((tid & 63) == 0) sred[4 + (tid >> 6)] = s;
    __syncthreads();
    s = sred[4] + sred[5] + sred[6] + sred[7];
    float inv = 1.f / s;
    float* wb = wout + b * TT;
    for (int t = tid; t < TT; t += 256) {
        float e = mb[t] ? -INFINITY : eb[t];
        wb[t] = expf(e - m) * inv;
    }
}

// ---------------- K5: partial context (8 t-chunks of 125) ---------------------
#define TCH 125
__global__ __launch_bounds__(512) void k_ctx_partial(const float* __restrict__ enc,
                                                     const float* __restrict__ w,
                                                     float* __restrict__ partial) {
    int b = blockIdx.x, c = blockIdx.y;
    int e = threadIdx.x;
    __shared__ float sw[TCH];
    int tstart = c * TCH;
    if (threadIdx.x < TCH) sw[threadIdx.x] = w[b * TT + tstart + threadIdx.x];
    __syncthreads();
    const float* p = enc + ((size_t)b * TT + tstart) * ENCD + e;
    float acc = 0.f;
    #pragma unroll 5
    for (int t = 0; t < TCH; ++t)
        acc += sw[t] * p[(size_t)t * ENCD];
    partial[((b << 3) + c) * ENCD + e] = acc;
}

// ---------------- K6: reduce partials -> context ------------------------------
__global__ __launch_bounds__(512) void k_ctx_reduce(const float* __restrict__ partial,
                                                    float* __restrict__ ctx) {
    int b = blockIdx.x, e = threadIdx.x;
    float s = 0.f;
    #pragma unroll
    for (int c = 0; c < 8; ++c) s += partial[((b << 3) + c) * ENCD + e];
    ctx[b * ENCD + e] = s;
}

// ---------------- launcher ----------------------------------------------------
extern "C" void kernel_launch(void* const* d_in, const int* in_sizes, int n_in,
                              void* d_out, int out_size, void* d_ws, size_t ws_size,
                              hipStream_t stream) {
    const float* dh   = (const float*)d_in[0];
    const float* enc  = (const float*)d_in[1];
    const float* pw   = (const float*)d_in[2];
    const float* pwc  = (const float*)d_in[3];
    const unsigned char* mask = (const unsigned char*)d_in[4];
    const float* cw   = (const float*)d_in[5];
    const float* lpw  = (const float*)d_in[6];
    const float* qw   = (const float*)d_in[7];
    const float* kw   = (const float*)d_in[8];
    const float* vw   = (const float*)d_in[9];

    float* out_ctx = (float*)d_out;                 // (64, 512)
    float* out_w   = out_ctx + BB * ENCD;           // (64, 1000)

    float* wsf   = (float*)d_ws;
    float*  q     = wsf;                             // 8192 f
    float*  energ = wsf + 8192;                      // 64000 f
    float*  part  = wsf + 8192 + 64000;              // 32768 f
    ushort* kwbF  = (ushort*)(wsf + 8192 + 64000 + 32768);  // 73728 bf16

    k_prep    <<<dim3(32),    dim3(256), 0, stream>>>(kw, kwbF);
    k_prepW2  <<<dim3(4),     dim3(256), 0, stream>>>(cw, lpw, kwbF);
    k_query   <<<dim3(BB),    dim3(128), 0, stream>>>(dh, qw, q);
    k_energies<<<dim3(BB, 8), dim3(512), 0, stream>>>(enc, pw, pwc, kwbF, vw, q, energ);
    k_softmax <<<dim3(BB),    dim3(256), 0, stream>>>(energ, mask, out_w);
    k_ctx_partial<<<dim3(BB, 8), dim3(512), 0, stream>>>(enc, out_w, part);
    k_ctx_reduce <<<dim3(BB),    dim3(512), 0, stream>>>(part, out_ctx);
}

// Round 10
// 91.860 us; speedup vs baseline: 1.5897x; 1.0476x over previous
//
#include <hip/hip_runtime.h>
#include <hip/hip_bf16.h>
#include <math.h>

#define BB   64
#define TT   1000
#define DEC  1024
#define ENCD 512
#define ATT  128
#define FILT 32
#define KSZ  31
#define PADW 15
#define BT   64    // t-tile per block
#define KC   64    // K chunk
#define XWN  96    // x-window alloc (94 used)

typedef __attribute__((ext_vector_type(8))) short bf16x8;
typedef __attribute__((ext_vector_type(4))) float f32x4;

static __device__ __forceinline__ ushort f2bf(float f) {
    union { float f; unsigned u; } v; v.f = f;
    unsigned r = (v.u + 0x7FFFu + ((v.u >> 16) & 1u)) >> 16;   // RNE
    return (ushort)r;
}

static __device__ __forceinline__ float fast_tanh(float x) {
    float e = __expf(2.f * x);
    return 1.f - 2.f * __builtin_amdgcn_rcpf(e + 1.f);
}

// async global->LDS, 16B per lane; LDS dest = wave-uniform base + lane*16
static __device__ __forceinline__ void gl2lds16(const void* g, void* l) {
    __builtin_amdgcn_global_load_lds(
        (const __attribute__((address_space(1))) unsigned*)g,
        (__attribute__((address_space(3))) unsigned*)l, 16, 0, 0);
}

// ---------------- K0: pack key_w (chunks 0..7) + W2 (chunk 8), frag-major -----
// element index = (((c*2+ks)*8 + n)*64 + lane)*8 + j
//   a = n*16 + (lane&15),  k = c*64 + ks*32 + (lane>>4)*8 + j
__global__ __launch_bounds__(256) void k_prep(const float* __restrict__ kw,
                                              const float* __restrict__ cw,
                                              const float* __restrict__ lpw,
                                              ushort* __restrict__ kwbF) {
    if (blockIdx.x < 32) {
        int idx = blockIdx.x * 256 + threadIdx.x;     // 0..8191
        int l  = idx & 63;
        int n  = (idx >> 6) & 7;
        int ks = (idx >> 9) & 1;
        int c  = idx >> 10;
        int a  = n * 16 + (l & 15);
        int k0 = c * 64 + ks * 32 + (l >> 4) * 8;
        ushort u[8];
        #pragma unroll
        for (int j = 0; j < 8; ++j) u[j] = f2bf(kw[a * ENCD + k0 + j]);
        *(uint4*)&kwbF[(size_t)idx * 8] = *(const uint4*)u;
    } else {
        // W2[c][k][a] = sum_f conv_w[f][c][k] * loc_proj_w[a][f];  k==31 row = 0
        int idx = (blockIdx.x - 32) * 256 + threadIdx.x;   // 0..1023
        int l  = idx & 63;
        int n  = (idx >> 6) & 7;
        int ks = (idx >> 9) & 1;                      // conv input channel
        int a  = n * 16 + (l & 15);
        int s  = l >> 4;
        ushort u[8];
        #pragma unroll
        for (int j = 0; j < 8; ++j) {
            int k = s * 8 + j;
            float v = 0.f;
            if (k < KSZ) {
                #pragma unroll
                for (int f = 0; f < FILT; ++f)
                    v += cw[(f * 2 + ks) * KSZ + k] * lpw[a * FILT + f];
            }
            u[j] = f2bf(v);
        }
        *(uint4*)&kwbF[(size_t)(((16 + ks) * 8 + n) * 64 + l) * 8] = *(const uint4*)u;
    }
}

// ---------------- K1: query = decoder_hidden @ query_w^T  (64 x 128) ----------
__global__ __launch_bounds__(128) void k_query(const float* __restrict__ dh,
                                               const float* __restrict__ qw,
                                               float* __restrict__ q) {
    int b = blockIdx.x, a = threadIdx.x;
    const float* dhb = dh + b * DEC;
    const float* qwa = qw + a * DEC;
    float s = 0.f;
    #pragma unroll 4
    for (int k = 0; k < DEC; k += 4) {
        float4 x = *(const float4*)&dhb[k];
        float4 w = *(const float4*)&qwa[k];
        s += x.x * w.x + x.y * w.y + x.z * w.z + x.w * w.w;
    }
    q[b * ATT + a] = s;
}

// ---------------- K3: MFMA GEMM over K=576, BT=64, 4 blocks/CU ----------------
// A tile: f32 [64 rows][16 x 16B-units], unit pos swizzled c4' = c4 ^ ((row&7)<<1),
// staged via global_load_lds with pre-swizzled per-lane SOURCE (linear LDS dest).
__global__ __launch_bounds__(256) void k_energies(
    const float* __restrict__ enc, const float* __restrict__ pw,
    const float* __restrict__ pwc, const ushort* __restrict__ kwbF,
    const float* __restrict__ vw, const float* __restrict__ q,
    float* __restrict__ energ)
{
    __shared__ __align__(16) float  Ab[BT * 64];        // 16 KB f32 swizzled
    __shared__ __align__(16) ushort Bb[2 * 8 * 64 * 8]; // 16 KB frag-major linear
    __shared__ __align__(16) float  xw[2][XWN];         // 0.75 KB im2col window

    const int b   = blockIdx.x;
    const int t0  = blockIdx.y * BT;
    const int tid = threadIdx.x;
    const int w   = tid >> 6;        // 4 waves
    const int l   = tid & 63;
    const int r   = l & 15;
    const int sl  = l >> 4;
    const int row = w * 16 + r;      // wave's t-row for MFMA reads (0..63)

    const float* encb = enc + (size_t)b * TT * ENCD;

    // per-lane pre-swizzled A source pointers (issue j covers rows (j*4+w)*4 .. +3)
    const float* aSrc[4];
    #pragma unroll
    for (int j = 0; j < 4; ++j) {
        int rw  = (j * 4 + w) * 4 + (l >> 4);          // row this lane feeds
        int c4  = (l & 15) ^ ((rw & 7) << 1);          // inverse-swizzled source unit
        int tg  = t0 + rw; if (tg >= TT) tg = TT - 1;
        aSrc[j] = encb + (size_t)tg * ENCD + c4 * 4;
    }

    // ---- stage x-window (zero-padded; finite everywhere) ----
    for (int i = tid; i < 2 * XWN; i += 256) {
        int c  = i / XWN;
        int ii = i - c * XWN;
        int tg = t0 + ii - PADW;
        const float* src = c ? pwc : pw;
        xw[c][ii] = (ii < BT + KSZ - 1 && tg >= 0 && tg < TT) ? src[b * TT + tg] : 0.f;
    }

    f32x4 acc[8];
    #pragma unroll
    for (int n = 0; n < 8; ++n) acc[n] = (f32x4){0.f, 0.f, 0.f, 0.f};

    for (int c = 0; c < 9; ++c) {
        if (c) __syncthreads();              // WAR: previous compute done with buffers
        // stage B chunk c (linear frag-major): 4 x 4 KB
        #pragma unroll
        for (int j = 0; j < 4; ++j)
            gl2lds16(kwbF + (size_t)c * 8192 + (size_t)(tid + j * 256) * 8,
                     &Bb[(size_t)(w * 64 + j * 256) * 8]);
        // stage A chunk c (enc chunks only)
        if (c < 8) {
            #pragma unroll
            for (int j = 0; j < 4; ++j)
                gl2lds16(aSrc[j] + c * KC, (char*)Ab + (j * 4 + w) * 1024);
        }
        __syncthreads();                     // drains vmcnt(0): buffers ready

        #pragma unroll
        for (int ks = 0; ks < 2; ++ks) {
            bf16x8 af;
            if (c < 8) {
                int s   = ks * 4 + sl;
                int c4p = (2 * s) ^ ((row & 7) << 1);
                const char* ap = (const char*)Ab + row * 256 + c4p * 16;
                float4 alo = *(const float4*)ap;
                float4 ahi = *(const float4*)(ap + 16);
                ushort u[8] = { f2bf(alo.x), f2bf(alo.y), f2bf(alo.z), f2bf(alo.w),
                                f2bf(ahi.x), f2bf(ahi.y), f2bf(ahi.z), f2bf(ahi.w) };
                af = *(const bf16x8*)u;
            } else {
                // im2col fragment: A[t][ks*32 + sl*8 + j] = xw[ks][t + sl*8 + j]
                const float* xp = &xw[ks][row + sl * 8];
                ushort u[8] = { f2bf(xp[0]), f2bf(xp[1]), f2bf(xp[2]), f2bf(xp[3]),
                                f2bf(xp[4]), f2bf(xp[5]), f2bf(xp[6]), f2bf(xp[7]) };
                af = *(const bf16x8*)u;
            }
            #pragma unroll
            for (int n = 0; n < 8; ++n) {
                bf16x8 bv = *(const bf16x8*)&Bb[(size_t)((ks * 8 + n) * 64 + l) * 8];
                acc[n] = __builtin_amdgcn_mfma_f32_16x16x32_bf16(af, bv, acc[n], 0, 0, 0);
            }
        }
    }

    // ---- epilogue: + query, tanh, v-dot, reduce over a (16 lanes) ----
    const float* qb = q + b * ATT;
    float pe[4];
    #pragma unroll
    for (int rr = 0; rr < 4; ++rr) pe[rr] = 0.f;
    #pragma unroll
    for (int n = 0; n < 8; ++n) {
        int a = n * 16 + r;
        float vvn = vw[a];
        float qvn = qb[a];
        #pragma unroll
        for (int rr = 0; rr < 4; ++rr)
            pe[rr] += vvn * fast_tanh(acc[n][rr] + qvn);
    }
    #pragma unroll
    for (int m = 1; m < 16; m <<= 1) {
        #pragma unroll
        for (int rr = 0; rr < 4; ++rr)
            pe[rr] += __shfl_xor(pe[rr], m, 64);
    }
    if (r == 0) {
        #pragma unroll
        for (int rr = 0; rr < 4; ++rr) {
            int t = t0 + w * 16 + sl * 4 + rr;
            if (t < TT) energ[b * TT + t] = pe[rr];
        }
    }
}

// ---------------- K4: softmax over T per batch row ----------------------------
__global__ __launch_bounds__(256) void k_softmax(const float* __restrict__ energ,
                                                 const unsigned char* __restrict__ mask,
                                                 float* __restrict__ wout) {
    int b = blockIdx.x, tid = threadIdx.x;
    __shared__ float sred[8];
    const float* eb = energ + b * TT;
    const unsigned char* mb = mask + b * TT;
    float m = -INFINITY;
    for (int t = tid; t < TT; t += 256) {
        float e = mb[t] ? -INFINITY : eb[t];
        m = fmaxf(m, e);
    }
    #pragma unroll
    for (int off = 32; off; off >>= 1) m = fmaxf(m, __shfl_xor(m, off, 64));
    if ((tid & 63) == 0) sred[tid >> 6] = m;
    __syncthreads();
    m = fmaxf(fmaxf(sred[0], sred[1]), fmaxf(sred[2], sred[3]));
    float s = 0.f;
    for (int t = tid; t < TT; t += 256) {
        float e = mb[t] ? -INFINITY : eb[t];
        s += expf(e - m);
    }
    #pragma unroll
    for (int off = 32; off; off >>= 1) s += __shfl_xor(s, off, 64);
    if ((tid & 63) == 0) sred[4 + (tid >> 6)] = s;
    __syncthreads();
    s = sred[4] + sred[5] + sred[6] + sred[7];
    float inv = 1.f / s;
    float* wb = wout + b * TT;
    for (int t = tid; t < TT; t += 256) {
        float e = mb[t] ? -INFINITY : eb[t];
        wb[t] = expf(e - m) * inv;
    }
}

// ---------------- K5: partial context (8 t-chunks of 125, float4 loads) -------
#define TCH 125
__global__ __launch_bounds__(512) void k_ctx_partial(const float* __restrict__ enc,
                                                     const float* __restrict__ w,
                                                     float* __restrict__ partial) {
    int b = blockIdx.x, c = blockIdx.y;
    int e4 = threadIdx.x & 127;      // float4 column
    int g  = threadIdx.x >> 7;       // 0..3 t-stripe
    __shared__ float sw[TCH];
    int tstart = c * TCH;
    if (threadIdx.x < TCH) sw[threadIdx.x] = w[b * TT + tstart + threadIdx.x];
    __syncthreads();
    const float* p = enc + ((size_t)b * TT + tstart) * ENCD;
    float4 acc = make_float4(0.f, 0.f, 0.f, 0.f);
    for (int t = g; t < TCH; t += 4) {
        float s = sw[t];
        float4 v = *(const float4*)(p + (size_t)t * ENCD + e4 * 4);
        acc.x += s * v.x; acc.y += s * v.y; acc.z += s * v.z; acc.w += s * v.w;
    }
    *(float4*)&partial[(size_t)(((b * 8 + c) * 4 + g)) * ENCD + e4 * 4] = acc;
}

// ---------------- K6: reduce 32 partials -> context ---------------------------
__global__ __launch_bounds__(512) void k_ctx_reduce(const float* __restrict__ partial,
                                                    float* __restrict__ ctx) {
    int b = blockIdx.x, e = threadIdx.x;
    float s = 0.f;
    #pragma unroll
    for (int i = 0; i < 32; ++i) s += partial[(size_t)(b * 32 + i) * ENCD + e];
    ctx[b * ENCD + e] = s;
}

// ---------------- launcher ----------------------------------------------------
extern "C" void kernel_launch(void* const* d_in, const int* in_sizes, int n_in,
                              void* d_out, int out_size, void* d_ws, size_t ws_size,
                              hipStream_t stream) {
    const float* dh   = (const float*)d_in[0];
    const float* enc  = (const float*)d_in[1];
    const float* pw   = (const float*)d_in[2];
    const float* pwc  = (const float*)d_in[3];
    const unsigned char* mask = (const unsigned char*)d_in[4];
    const float* cw   = (const float*)d_in[5];
    const float* lpw  = (const float*)d_in[6];
    const float* qw   = (const float*)d_in[7];
    const float* kw   = (const float*)d_in[8];
    const float* vw   = (const float*)d_in[9];

    float* out_ctx = (float*)d_out;                 // (64, 512)
    float* out_w   = out_ctx + BB * ENCD;           // (64, 1000)

    float* wsf   = (float*)d_ws;
    float*  q     = wsf;                             // 8192 f
    float*  energ = wsf + 8192;                      // 64000 f
    float*  part  = wsf + 8192 + 64000;              // 64*32*512 f
    ushort* kwbF  = (ushort*)(wsf + 8192 + 64000 + 64 * 32 * 512);  // 73728 bf16

    k_prep    <<<dim3(36),     dim3(256), 0, stream>>>(kw, cw, lpw, kwbF);
    k_query   <<<dim3(BB),     dim3(128), 0, stream>>>(dh, qw, q);
    k_energies<<<dim3(BB, 16), dim3(256), 0, stream>>>(enc, pw, pwc, kwbF, vw, q, energ);
    k_softmax <<<dim3(BB),     dim3(256), 0, stream>>>(energ, mask, out_w);
    k_ctx_partial<<<dim3(BB, 8), dim3(512), 0, stream>>>(enc, out_w, part);
    k_ctx_reduce <<<dim3(BB),    dim3(512), 0, stream>>>(part, out_ctx);
}